// Round 8
// baseline (256.099 us; speedup 1.0000x reference)
//
#include <hip/hip_runtime.h>

typedef __bf16 bf16;
typedef __bf16 bf16x8 __attribute__((ext_vector_type(8)));
typedef float  f32x4  __attribute__((ext_vector_type(4)));
typedef unsigned u32x4 __attribute__((ext_vector_type(4)));

#define B_  8
#define N_  2048
#define D_  512
#define H_  8
#define DH_ 64
static constexpr float SC2 = 0.18033688011112042f; // (1/8) * log2(e)

#if defined(__has_builtin)
#if __has_builtin(__builtin_amdgcn_exp2f)
#define EXP2(x) __builtin_amdgcn_exp2f(x)
#else
#define EXP2(x) exp2f(x)
#endif
#else
#define EXP2(x) exp2f(x)
#endif

#if defined(__has_builtin)
#if __has_builtin(__builtin_amdgcn_permlane32_swap) && __has_builtin(__builtin_amdgcn_permlane16_swap)
#define HAVE_PLSWAP 1
#endif
#endif

__device__ __forceinline__ f32x4 mfma16(bf16x8 a, bf16x8 b, f32x4 c) {
  return __builtin_amdgcn_mfma_f32_16x16x32_bf16(a, b, c, 0, 0, 0);
}

__device__ __forceinline__ void gload_lds16(const void* g, void* l) {
  __builtin_amdgcn_global_load_lds((__attribute__((address_space(1))) void*)g,
                                   (__attribute__((address_space(3))) void*)l, 16, 0, 0);
}

__device__ __forceinline__ unsigned cvt_pk_bf16(float lo, float hi) {
  unsigned r;
  asm("v_cvt_pk_bf16_f32 %0, %1, %2" : "=v"(r) : "v"(lo), "v"(hi));
  return r;
}

// ---- convert x (f32) -> bf16, 8 elems/thread ----
__global__ void k_cvt_x(const float* __restrict__ x, bf16* __restrict__ xb) {
  int i = blockIdx.x * blockDim.x + threadIdx.x;
  const float4* p = (const float4*)x;
  float4 a = p[2*i], b = p[2*i+1];
  bf16x8 o;
  o[0]=(bf16)a.x; o[1]=(bf16)a.y; o[2]=(bf16)a.z; o[3]=(bf16)a.w;
  o[4]=(bf16)b.x; o[5]=(bf16)b.y; o[6]=(bf16)b.z; o[7]=(bf16)b.w;
  ((bf16x8*)xb)[i] = o;
}

// ---- transpose-convert one 512x512 f32 weight -> bf16 W^T ----
__global__ void k_wt(const float* __restrict__ w, bf16* __restrict__ wt) {
  __shared__ float t[64][65];
  const int c0 = blockIdx.x * 64, k0 = blockIdx.y * 64;
  const int r = threadIdx.x >> 2, q4 = (threadIdx.x & 3) * 16;
#pragma unroll
  for (int j = 0; j < 16; j += 4) {
    float4 v = *(const float4*)(w + (k0 + r) * 512 + c0 + q4 + j);
    t[r][q4+j] = v.x; t[r][q4+j+1] = v.y; t[r][q4+j+2] = v.z; t[r][q4+j+3] = v.w;
  }
  __syncthreads();
  const int c = threadIdx.x >> 2, kq = (threadIdx.x & 3) * 16;
  bf16x8 o0, o1;
#pragma unroll
  for (int j = 0; j < 8; ++j) { o0[j] = (bf16)t[kq+j][c]; o1[j] = (bf16)t[kq+8+j][c]; }
  *(bf16x8*)(wt + (c0 + c) * 512 + k0 + kq) = o0;
  *(bf16x8*)(wt + (c0 + c) * 512 + k0 + kq + 8) = o1;
}

// ---- 128x128 tile GEMM, K=512 ----
template<int MODE>
__global__ void k_gemm(const bf16* __restrict__ A, const bf16* __restrict__ Bt,
                       bf16* __restrict__ qo, bf16* __restrict__ ko, bf16* __restrict__ vo,
                       float* __restrict__ outp, const float* __restrict__ bo) {
  __shared__ bf16 lA[128 * 64];
  __shared__ bf16 lB[128 * 64];
  const int tid = threadIdx.x;
  const int wid = tid >> 6, lane = tid & 63;
  const int l15 = lane & 15, lq = lane >> 4;
  const int wr = wid >> 1, wc = wid & 1;
  const long long rowtile = (long long)blockIdx.x * 128;
  const long long coltile = (long long)blockIdx.y * 128;

  const bf16* gA[4]; const bf16* gB[4];
  bf16* lAc[4]; bf16* lBc[4];
#pragma unroll
  for (int i = 0; i < 4; ++i) {
    int ci = wid * 4 + i;
    int row = ci * 8 + (lane >> 3);
    int c8 = (lane & 7) ^ (row & 7);
    gA[i] = A + (rowtile + row) * 512 + c8 * 8;
    gB[i] = Bt + (coltile + row) * 512 + c8 * 8;
    lAc[i] = &lA[ci * 512];
    lBc[i] = &lB[ci * 512];
  }
  unsigned aoff[4][2], boff[4][2];
#pragma unroll
  for (int mi = 0; mi < 4; ++mi) {
#pragma unroll
    for (int ks = 0; ks < 2; ++ks) {
      int R = l15 + 16 * mi + 64 * wr;
      aoff[mi][ks] = R * 128 + ((((ks << 2) | lq) ^ (R & 7)) << 4);
      int Rb = l15 + 16 * mi + 64 * wc;
      boff[mi][ks] = Rb * 128 + ((((ks << 2) | lq) ^ (Rb & 7)) << 4);
    }
  }
  f32x4 acc[4][4] = {};
  for (int kt = 0; kt < 8; ++kt) {
#pragma unroll
    for (int i = 0; i < 4; ++i) gload_lds16(gA[i], lAc[i]);
#pragma unroll
    for (int i = 0; i < 4; ++i) gload_lds16(gB[i], lBc[i]);
#pragma unroll
    for (int i = 0; i < 4; ++i) { gA[i] += 64; gB[i] += 64; }
    __syncthreads();
#pragma unroll
    for (int ks = 0; ks < 2; ++ks) {
      bf16x8 af[4], bfr[4];
#pragma unroll
      for (int mi = 0; mi < 4; ++mi) af[mi] = *(const bf16x8*)((const char*)lA + aoff[mi][ks]);
#pragma unroll
      for (int nf = 0; nf < 4; ++nf) bfr[nf] = *(const bf16x8*)((const char*)lB + boff[nf][ks]);
#pragma unroll
      for (int mi = 0; mi < 4; ++mi)
#pragma unroll
        for (int nf = 0; nf < 4; ++nf)
          acc[mi][nf] = mfma16(af[mi], bfr[nf], acc[mi][nf]);
    }
    __syncthreads();
  }
  if (MODE == 0) {
#pragma unroll
    for (int nf = 0; nf < 4; ++nf) {
      const int col = (int)coltile + 64 * wc + nf * 16 + l15;
      const int mat = col >> 9, c5 = col & 511, hh = c5 >> 6, dh = c5 & 63;
#pragma unroll
      for (int mi = 0; mi < 4; ++mi) {
#pragma unroll
        for (int r = 0; r < 4; ++r) {
          const int R = (int)rowtile + 64 * wr + mi * 16 + lq * 4 + r;
          const int bb = R >> 11, n = R & 2047;
          const bf16 bv = (bf16)acc[mi][nf][r];
          const long long bh = bb * 8 + hh;
          if (mat == 0)      qo[(bh * 2048 + n) * 64 + dh] = bv;
          else if (mat == 1) ko[(bh * 2048 + n) * 64 + dh] = bv;
          else               vo[(bh * 64 + dh) * 2048 + n] = bv;
        }
      }
    }
  } else {
#pragma unroll
    for (int nf = 0; nf < 4; ++nf) {
      const int col = (int)coltile + 64 * wc + nf * 16 + l15;
      const float bias = bo[col];
#pragma unroll
      for (int mi = 0; mi < 4; ++mi)
#pragma unroll
        for (int r = 0; r < 4; ++r) {
          const long long R = rowtile + 64 * wr + mi * 16 + lq * 4 + r;
          outp[R * 512 + col] = acc[mi][nf][r] + bias;
        }
    }
  }
}

// ---- flash attention v8 ----
// block = (b,h, qtile of 128 rows); 256 thr = 4 waves x 32 q-rows (mi=0,1).
// Swapped QK^T => K/V fragments are mi-independent: the same 8 K-reads and
// 8 V-reads feed 2x the MFMAs -> total LDS read traffic HALVED vs v7.
// K/V LDS double-buffer (gload_lds, swizzled src), 1 barrier per jt.
// Mask: 2 reg banks (mi=0/1), next-jt loads issued right after consumption.
__global__ __launch_bounds__(256, 3) void k_attn(
    const bf16* __restrict__ qb, const bf16* __restrict__ kb, const bf16* __restrict__ vt,
    const float* __restrict__ mask, bf16* __restrict__ ao) {
  __shared__ __align__(16) bf16 kvls[2][2][64 * 64];   // [buf][K/V], 32 KB
  const int tid = threadIdx.x;
  const int lane = tid & 63;
  const int wid = tid >> 6;                 // 0..3
  const int l15 = lane & 15, lq = lane >> 4;
  const int p = blockIdx.x;
  const int xcd = p & 7, kk = p >> 3;
  const int g = xcd * 16 + (kk >> 3), h = kk & 7;
  const int b = g >> 4, qt = g & 15;
  const long long bh = b * 8 + h;
  const bf16* Q = qb + bh * (2048ll * 64);
  const bf16* K = kb + bh * (2048ll * 64);
  const bf16* V = vt + bh * (64ll * 2048);
  const int qrow0 = qt * 128 + wid * 32;
  const float* mptr0 = mask + ((long long)b * 2048 + qrow0 + l15) * 2048 + lq * 4;
  const float* mptr1 = mptr0 + 16 * 2048;

  // staging: 256 thr x 2 chunks x 16B per tile (K and V); swizzled source
  const int row0 = tid >> 3, row1 = row0 + 32;
  const int sc = (tid & 7) ^ (row0 & 7);   // row1&7 == row0&7
  const bf16* kg0 = K + row0 * 64 + sc * 8;
  const bf16* vg0 = V + row0 * 2048 + sc * 8;
  const bf16* vg1 = V + row1 * 2048 + sc * 8;

  bf16x8 qf[2][2];
#pragma unroll
  for (int mi = 0; mi < 2; ++mi)
#pragma unroll
    for (int ks = 0; ks < 2; ++ks)
      qf[mi][ks] = *(const bf16x8*)(Q + (qrow0 + mi * 16 + l15) * 64 + ks * 32 + lq * 8);

  f32x4 o[2][4] = {};
  float lsum0 = 0.f, lsum1 = 0.f;
  f32x4 mA[4], mB[4];

  auto stageKV = [&](int buf, int jt) {
    gload_lds16(kg0 + jt * 4096,        &kvls[buf][0][tid * 8]);
    gload_lds16(kg0 + jt * 4096 + 2048, &kvls[buf][0][tid * 8 + 2048]);
    gload_lds16(vg0 + jt * 64,          &kvls[buf][1][tid * 8]);
    gload_lds16(vg1 + jt * 64,          &kvls[buf][1][tid * 8 + 2048]);
  };

  // softmax half: exp(s)*norm tracking, next-jt mask prefetch, P exchange
  auto smax = [&](f32x4 (&m)[4], const float* mp, const f32x4 (&sm)[4], float& ls,
                  bf16x8& pA, bf16x8& pB, bool pref, int jbn) {
    unsigned w[4][2];
#pragma unroll
    for (int nf = 0; nf < 4; ++nf) {
      float mp0 = fmaf(m[nf][0], SC2, SC2);
      float mp1 = fmaf(m[nf][1], SC2, SC2);
      float mp2 = fmaf(m[nf][2], SC2, SC2);
      float mp3 = fmaf(m[nf][3], SC2, SC2);
      float pe0 = EXP2(sm[nf][0] * mp0);
      float pe1 = EXP2(sm[nf][1] * mp1);
      float pe2 = EXP2(sm[nf][2] * mp2);
      float pe3 = EXP2(sm[nf][3] * mp3);
      ls += ((pe0 + pe1) + (pe2 + pe3));
      w[nf][0] = cvt_pk_bf16(pe0, pe1);
      w[nf][1] = cvt_pk_bf16(pe2, pe3);
    }
    if (pref) {
#pragma unroll
      for (int nf = 0; nf < 4; ++nf)
        m[nf] = *(const f32x4*)(mp + jbn + nf * 16);
    }
    unsigned pa0[4], pa1[4];
#ifdef HAVE_PLSWAP
#pragma unroll
    for (int t = 0; t < 2; ++t) {
      auto sA = __builtin_amdgcn_permlane32_swap(w[0][t], w[1][t], false, false);
      auto sB = __builtin_amdgcn_permlane16_swap(sA[0], sA[1], false, false);
      pa0[t] = sB[0]; pa0[t + 2] = sB[1];
      auto sC = __builtin_amdgcn_permlane32_swap(w[2][t], w[3][t], false, false);
      auto sD = __builtin_amdgcn_permlane16_swap(sC[0], sC[1], false, false);
      pa1[t] = sD[0]; pa1[t + 2] = sD[1];
    }
#else
    {
      const int basel = l15 + ((lq & 1) << 5);
#pragma unroll
      for (int t = 0; t < 2; ++t) {
        int sel0 = (lq & 2) ? (int)w[1][t] : (int)w[0][t];
        int sel1 = (lq & 2) ? (int)w[3][t] : (int)w[2][t];
        pa0[t]     = (unsigned)__shfl(sel0, basel);
        pa0[t + 2] = (unsigned)__shfl(sel0, basel + 16);
        pa1[t]     = (unsigned)__shfl(sel1, basel);
        pa1[t + 2] = (unsigned)__shfl(sel1, basel + 16);
      }
    }
#endif
    u32x4 ua = {pa0[0], pa0[1], pa0[2], pa0[3]};
    u32x4 ub = {pa1[0], pa1[1], pa1[2], pa1[3]};
    pA = __builtin_bit_cast(bf16x8, ua);
    pB = __builtin_bit_cast(bf16x8, ub);
  };

  // prologue: stage tile 0; load mask (jt=0) for both mi
  stageKV(0, 0);
#pragma unroll
  for (int nf = 0; nf < 4; ++nf) {
    mA[nf] = *(const f32x4*)(mptr0 + nf * 16);
    mB[nf] = *(const f32x4*)(mptr1 + nf * 16);
  }
  __syncthreads();

  for (int jt = 0; jt < 32; ++jt) {
    const int buf = jt & 1;
    const bool morejt = (jt + 1 < 32);
    if (morejt) stageKV(buf ^ 1, jt + 1);
    const bf16* kbL = &kvls[buf][0][0];
    const bf16* vbL = &kvls[buf][1][0];

    // QK^T: A=K rows n (mi-independent), B=Q[mi] -> s[mi][nf]: q=l15, n=nf*16+lq*4+r
    f32x4 s[2][4];
    {
      bf16x8 kf0[4], kf1[4];
#pragma unroll
      for (int nf = 0; nf < 4; ++nf) {
        const int row = nf * 16 + l15;
        kf0[nf] = *(const bf16x8*)(kbL + row * 64 + ((lq ^ (row & 7)) << 3));
        kf1[nf] = *(const bf16x8*)(kbL + row * 64 + (((4 + lq) ^ (row & 7)) << 3));
      }
#pragma unroll
      for (int mi = 0; mi < 2; ++mi)
#pragma unroll
        for (int nf = 0; nf < 4; ++nf) {
          f32x4 z = {0.f, 0.f, 0.f, 0.f};
          s[mi][nf] = mfma16(kf0[nf], qf[mi][0], z);
        }
#pragma unroll
      for (int mi = 0; mi < 2; ++mi)
#pragma unroll
        for (int nf = 0; nf < 4; ++nf)
          s[mi][nf] = mfma16(kf1[nf], qf[mi][1], s[mi][nf]);
    }

    bf16x8 paA0, paB0, paA1, paB1;
    smax(mA, mptr0, s[0], lsum0, paA0, paB0, morejt, (jt + 1) * 64);
    smax(mB, mptr1, s[1], lsum1, paA1, paB1, morejt, (jt + 1) * 64);

    // PV: shared V fragments feed both mi
#pragma unroll
    for (int nf = 0; nf < 4; ++nf) {
      const int row = nf * 16 + l15;
      const bf16x8 vf = *(const bf16x8*)(vbL + row * 64 + ((lq ^ (row & 7)) << 3));
      o[0][nf] = mfma16(paA0, vf, o[0][nf]);
      o[1][nf] = mfma16(paA1, vf, o[1][nf]);
    }
#pragma unroll
    for (int nf = 0; nf < 4; ++nf) {
      const int row = nf * 16 + l15;
      const bf16x8 vf = *(const bf16x8*)(vbL + row * 64 + (((4 + lq) ^ (row & 7)) << 3));
      o[0][nf] = mfma16(paB0, vf, o[0][nf]);
      o[1][nf] = mfma16(paB1, vf, o[1][nf]);
    }
    __syncthreads();
  }

  // normalize: lsum holds q=l15 partial over this lane's n-slice
  float v0 = lsum0, v1 = lsum1;
  v0 += __shfl_xor(v0, 16); v0 += __shfl_xor(v0, 32);
  v1 += __shfl_xor(v1, 16); v1 += __shfl_xor(v1, 32);
  const float ri0 = 1.0f / v0, ri1 = 1.0f / v1;
  float rv[2][4];
#pragma unroll
  for (int r = 0; r < 4; ++r) {
    rv[0][r] = __shfl(ri0, ((lane & 48) >> 2) + r);   // rinv of q = lq*4+r
    rv[1][r] = __shfl(ri1, ((lane & 48) >> 2) + r);
  }
#pragma unroll
  for (int mi = 0; mi < 2; ++mi)
#pragma unroll
    for (int nf = 0; nf < 4; ++nf)
#pragma unroll
      for (int r = 0; r < 4; ++r) {
        const long long rowg = (long long)b * 2048 + qrow0 + mi * 16 + lq * 4 + r;
        ao[rowg * 512 + h * 64 + nf * 16 + l15] = (bf16)(o[mi][nf][r] * rv[mi][r]);
      }
}

extern "C" void kernel_launch(void* const* d_in, const int* in_sizes, int n_in,
                              void* d_out, int out_size, void* d_ws, size_t ws_size,
                              hipStream_t stream) {
  const float* x    = (const float*)d_in[0];
  const float* mask = (const float*)d_in[1];
  const float* Wq   = (const float*)d_in[2];
  const float* Wk   = (const float*)d_in[3];
  const float* Wv   = (const float*)d_in[4];
  const float* Wo   = (const float*)d_in[5];
  const float* bo   = (const float*)d_in[6];
  float* out = (float*)d_out;
  char* ws = (char*)d_ws;

  const size_t SZ_XB = (size_t)16384 * 512 * 2;
  const size_t SZ_W3 = (size_t)1536 * 512 * 2;
  const size_t SZ_WO = (size_t)512 * 512 * 2;
  const size_t SZ_T  = (size_t)64 * 2048 * 64 * 2;

  bf16* xb    = (bf16*)ws;
  bf16* wqkvT = (bf16*)(ws + SZ_XB);
  bf16* woT   = (bf16*)(ws + SZ_XB + SZ_W3);
  bf16* qbuf  = (bf16*)(ws + SZ_XB + SZ_W3 + SZ_WO);
  bf16* kbuf  = (bf16*)((char*)qbuf + SZ_T);
  bf16* vtb   = (bf16*)((char*)kbuf + SZ_T);
  bf16* aob   = xb;  // x dead after QKV GEMM

  k_cvt_x<<<dim3(4096), dim3(256), 0, stream>>>(x, xb);
  k_wt<<<dim3(8, 8), dim3(256), 0, stream>>>(Wq, wqkvT);
  k_wt<<<dim3(8, 8), dim3(256), 0, stream>>>(Wk, wqkvT + 512 * 512);
  k_wt<<<dim3(8, 8), dim3(256), 0, stream>>>(Wv, wqkvT + 2 * 512 * 512);
  k_wt<<<dim3(8, 8), dim3(256), 0, stream>>>(Wo, woT);
  k_gemm<0><<<dim3(128, 12), dim3(256), 0, stream>>>(xb, wqkvT, qbuf, kbuf, vtb, nullptr, nullptr);
  k_attn<<<dim3(1024), dim3(256), 0, stream>>>(qbuf, kbuf, vtb, mask, aob);
  k_gemm<1><<<dim3(128, 4), dim3(256), 0, stream>>>(aob, woT, nullptr, nullptr, nullptr, out, bo);
}

// Round 9
// 252.446 us; speedup vs baseline: 1.0145x; 1.0145x over previous
//
#include <hip/hip_runtime.h>

typedef __bf16 bf16;
typedef __bf16 bf16x8 __attribute__((ext_vector_type(8)));
typedef float  f32x4  __attribute__((ext_vector_type(4)));
typedef unsigned u32x4 __attribute__((ext_vector_type(4)));

#define B_  8
#define N_  2048
#define D_  512
#define H_  8
#define DH_ 64
static constexpr float SC2 = 0.18033688011112042f; // (1/8) * log2(e)

#if defined(__has_builtin)
#if __has_builtin(__builtin_amdgcn_exp2f)
#define EXP2(x) __builtin_amdgcn_exp2f(x)
#else
#define EXP2(x) exp2f(x)
#endif
#else
#define EXP2(x) exp2f(x)
#endif

#if defined(__has_builtin)
#if __has_builtin(__builtin_amdgcn_permlane32_swap) && __has_builtin(__builtin_amdgcn_permlane16_swap)
#define HAVE_PLSWAP 1
#endif
#endif

__device__ __forceinline__ f32x4 mfma16(bf16x8 a, bf16x8 b, f32x4 c) {
  return __builtin_amdgcn_mfma_f32_16x16x32_bf16(a, b, c, 0, 0, 0);
}

__device__ __forceinline__ void gload_lds16(const void* g, void* l) {
  __builtin_amdgcn_global_load_lds((__attribute__((address_space(1))) void*)g,
                                   (__attribute__((address_space(3))) void*)l, 16, 0, 0);
}

__device__ __forceinline__ unsigned cvt_pk_bf16(float lo, float hi) {
  unsigned r;
  asm("v_cvt_pk_bf16_f32 %0, %1, %2" : "=v"(r) : "v"(lo), "v"(hi));
  return r;
}

// batched LDS read: compile-time offset immediate, forced issue order
#define DSR(dst, a, off) \
  asm volatile("ds_read_b128 %0, %1 offset:" off : "=v"(dst) : "v"(a))

// ---- convert x (f32) -> bf16, 8 elems/thread ----
__global__ void k_cvt_x(const float* __restrict__ x, bf16* __restrict__ xb) {
  int i = blockIdx.x * blockDim.x + threadIdx.x;
  const float4* p = (const float4*)x;
  float4 a = p[2*i], b = p[2*i+1];
  bf16x8 o;
  o[0]=(bf16)a.x; o[1]=(bf16)a.y; o[2]=(bf16)a.z; o[3]=(bf16)a.w;
  o[4]=(bf16)b.x; o[5]=(bf16)b.y; o[6]=(bf16)b.z; o[7]=(bf16)b.w;
  ((bf16x8*)xb)[i] = o;
}

// ---- transpose-convert one 512x512 f32 weight -> bf16 W^T ----
__global__ void k_wt(const float* __restrict__ w, bf16* __restrict__ wt) {
  __shared__ float t[64][65];
  const int c0 = blockIdx.x * 64, k0 = blockIdx.y * 64;
  const int r = threadIdx.x >> 2, q4 = (threadIdx.x & 3) * 16;
#pragma unroll
  for (int j = 0; j < 16; j += 4) {
    float4 v = *(const float4*)(w + (k0 + r) * 512 + c0 + q4 + j);
    t[r][q4+j] = v.x; t[r][q4+j+1] = v.y; t[r][q4+j+2] = v.z; t[r][q4+j+3] = v.w;
  }
  __syncthreads();
  const int c = threadIdx.x >> 2, kq = (threadIdx.x & 3) * 16;
  bf16x8 o0, o1;
#pragma unroll
  for (int j = 0; j < 8; ++j) { o0[j] = (bf16)t[kq+j][c]; o1[j] = (bf16)t[kq+8+j][c]; }
  *(bf16x8*)(wt + (c0 + c) * 512 + k0 + kq) = o0;
  *(bf16x8*)(wt + (c0 + c) * 512 + k0 + kq + 8) = o1;
}

// ---- 128x128 tile GEMM, K=512 ----
template<int MODE>
__global__ void k_gemm(const bf16* __restrict__ A, const bf16* __restrict__ Bt,
                       bf16* __restrict__ qo, bf16* __restrict__ ko, bf16* __restrict__ vo,
                       float* __restrict__ outp, const float* __restrict__ bo) {
  __shared__ bf16 lA[128 * 64];
  __shared__ bf16 lB[128 * 64];
  const int tid = threadIdx.x;
  const int wid = tid >> 6, lane = tid & 63;
  const int l15 = lane & 15, lq = lane >> 4;
  const int wr = wid >> 1, wc = wid & 1;
  const long long rowtile = (long long)blockIdx.x * 128;
  const long long coltile = (long long)blockIdx.y * 128;

  const bf16* gA[4]; const bf16* gB[4];
  bf16* lAc[4]; bf16* lBc[4];
#pragma unroll
  for (int i = 0; i < 4; ++i) {
    int ci = wid * 4 + i;
    int row = ci * 8 + (lane >> 3);
    int c8 = (lane & 7) ^ (row & 7);
    gA[i] = A + (rowtile + row) * 512 + c8 * 8;
    gB[i] = Bt + (coltile + row) * 512 + c8 * 8;
    lAc[i] = &lA[ci * 512];
    lBc[i] = &lB[ci * 512];
  }
  unsigned aoff[4][2], boff[4][2];
#pragma unroll
  for (int mi = 0; mi < 4; ++mi) {
#pragma unroll
    for (int ks = 0; ks < 2; ++ks) {
      int R = l15 + 16 * mi + 64 * wr;
      aoff[mi][ks] = R * 128 + ((((ks << 2) | lq) ^ (R & 7)) << 4);
      int Rb = l15 + 16 * mi + 64 * wc;
      boff[mi][ks] = Rb * 128 + ((((ks << 2) | lq) ^ (Rb & 7)) << 4);
    }
  }
  f32x4 acc[4][4] = {};
  for (int kt = 0; kt < 8; ++kt) {
#pragma unroll
    for (int i = 0; i < 4; ++i) gload_lds16(gA[i], lAc[i]);
#pragma unroll
    for (int i = 0; i < 4; ++i) gload_lds16(gB[i], lBc[i]);
#pragma unroll
    for (int i = 0; i < 4; ++i) { gA[i] += 64; gB[i] += 64; }
    __syncthreads();
#pragma unroll
    for (int ks = 0; ks < 2; ++ks) {
      bf16x8 af[4], bfr[4];
#pragma unroll
      for (int mi = 0; mi < 4; ++mi) af[mi] = *(const bf16x8*)((const char*)lA + aoff[mi][ks]);
#pragma unroll
      for (int nf = 0; nf < 4; ++nf) bfr[nf] = *(const bf16x8*)((const char*)lB + boff[nf][ks]);
#pragma unroll
      for (int mi = 0; mi < 4; ++mi)
#pragma unroll
        for (int nf = 0; nf < 4; ++nf)
          acc[mi][nf] = mfma16(af[mi], bfr[nf], acc[mi][nf]);
    }
    __syncthreads();
  }
  if (MODE == 0) {
#pragma unroll
    for (int nf = 0; nf < 4; ++nf) {
      const int col = (int)coltile + 64 * wc + nf * 16 + l15;
      const int mat = col >> 9, c5 = col & 511, hh = c5 >> 6, dh = c5 & 63;
#pragma unroll
      for (int mi = 0; mi < 4; ++mi) {
#pragma unroll
        for (int r = 0; r < 4; ++r) {
          const int R = (int)rowtile + 64 * wr + mi * 16 + lq * 4 + r;
          const int bb = R >> 11, n = R & 2047;
          const bf16 bv = (bf16)acc[mi][nf][r];
          const long long bh = bb * 8 + hh;
          if (mat == 0)      qo[(bh * 2048 + n) * 64 + dh] = bv;
          else if (mat == 1) ko[(bh * 2048 + n) * 64 + dh] = bv;
          else               vo[(bh * 64 + dh) * 2048 + n] = bv;
        }
      }
    }
  } else {
#pragma unroll
    for (int nf = 0; nf < 4; ++nf) {
      const int col = (int)coltile + 64 * wc + nf * 16 + l15;
      const float bias = bo[col];
#pragma unroll
      for (int mi = 0; mi < 4; ++mi)
#pragma unroll
        for (int r = 0; r < 4; ++r) {
          const long long R = rowtile + 64 * wr + mi * 16 + lq * 4 + r;
          outp[R * 512 + col] = acc[mi][nf][r] + bias;
        }
    }
  }
}

// ---- flash attention v9 ----
// v8 structure (256 thr = 4 waves x 32 q-rows, K/V LDS dbuf, in-reg P) but
// with asm-forced ILP: 8 ds_read_b128 batched per K/V phase (one base reg +
// offset immediates; swizzle term is nf-independent since row&7 == l15&7),
// lgkmcnt(0)+sched_barrier fences (rule #18). V reads issued before softmax
// so LDS latency hides under the VALU phase. Mask loads grouped at iter top.
__global__ __launch_bounds__(256, 3) void k_attn(
    const bf16* __restrict__ qb, const bf16* __restrict__ kb, const bf16* __restrict__ vt,
    const float* __restrict__ mask, bf16* __restrict__ ao) {
  __shared__ __align__(16) bf16 kvls[2][2][64 * 64];   // [buf][K/V]; buf stride 16KB
  const int tid = threadIdx.x;
  const int lane = tid & 63;
  const int wid = tid >> 6;                 // 0..3
  const int l15 = lane & 15, lq = lane >> 4;
  const int p = blockIdx.x;
  const int xcd = p & 7, kk = p >> 3;
  const int g = xcd * 16 + (kk >> 3), h = kk & 7;
  const int b = g >> 4, qt = g & 15;
  const long long bh = b * 8 + h;
  const bf16* Q = qb + bh * (2048ll * 64);
  const bf16* K = kb + bh * (2048ll * 64);
  const bf16* V = vt + bh * (64ll * 2048);
  const int qrow0 = qt * 128 + wid * 32;
  const float* mptr0 = mask + ((long long)b * 2048 + qrow0 + l15) * 2048 + lq * 4;
  const float* mptr1 = mptr0 + 16 * 2048;

  // staging (v8-proven): 256 thr x 2 chunks x 16B per tile; swizzled source
  const int row0 = tid >> 3;
  const int sc = (tid & 7) ^ (row0 & 7);
  const bf16* kg0 = K + row0 * 64 + sc * 8;
  const bf16* vg0 = V + row0 * 2048 + sc * 8;
  const bf16* vg1 = V + (row0 + 32) * 2048 + sc * 8;

  // LDS read bases: byte addr = buf*16384 + [K:0 / V:8192] + row*128 + swz
  // row = nf*16 + l15  ->  nf contributes offset nf*2048 (immediate);
  // swz = ((ks*4+lq) ^ (row&7))<<4 and row&7 == l15&7 (nf-independent).
  const unsigned lbase = (unsigned)(size_t)(&kvls[0][0][0]) + (unsigned)(l15 * 128);
  const unsigned aks0 = lbase + (((unsigned)(lq ^ (l15 & 7))) << 4);
  const unsigned aks1 = lbase + (((unsigned)((4 + lq) ^ (l15 & 7))) << 4);

  bf16x8 qf[2][2];
#pragma unroll
  for (int mi = 0; mi < 2; ++mi)
#pragma unroll
    for (int ks = 0; ks < 2; ++ks)
      qf[mi][ks] = *(const bf16x8*)(Q + (qrow0 + mi * 16 + l15) * 64 + ks * 32 + lq * 8);

  f32x4 o[2][4] = {};
  float lsum0 = 0.f, lsum1 = 0.f;

  auto stageKV = [&](int buf, int jt) {
    gload_lds16(kg0 + jt * 4096,        &kvls[buf][0][tid * 8]);
    gload_lds16(kg0 + jt * 4096 + 2048, &kvls[buf][0][tid * 8 + 2048]);
    gload_lds16(vg0 + jt * 64,          &kvls[buf][1][tid * 8]);
    gload_lds16(vg1 + jt * 64,          &kvls[buf][1][tid * 8 + 2048]);
  };

  // softmax half (v8-proven algebra): exp, lsum, cvt_pk + permlane exchange
  auto smax = [&](const f32x4 (&m)[4], const f32x4 (&sm)[4], float& ls,
                  bf16x8& pA, bf16x8& pB) {
    unsigned w[4][2];
#pragma unroll
    for (int nf = 0; nf < 4; ++nf) {
      float mp0 = fmaf(m[nf][0], SC2, SC2);
      float mp1 = fmaf(m[nf][1], SC2, SC2);
      float mp2 = fmaf(m[nf][2], SC2, SC2);
      float mp3 = fmaf(m[nf][3], SC2, SC2);
      float pe0 = EXP2(sm[nf][0] * mp0);
      float pe1 = EXP2(sm[nf][1] * mp1);
      float pe2 = EXP2(sm[nf][2] * mp2);
      float pe3 = EXP2(sm[nf][3] * mp3);
      ls += ((pe0 + pe1) + (pe2 + pe3));
      w[nf][0] = cvt_pk_bf16(pe0, pe1);
      w[nf][1] = cvt_pk_bf16(pe2, pe3);
    }
    unsigned pa0[4], pa1[4];
#ifdef HAVE_PLSWAP
#pragma unroll
    for (int t = 0; t < 2; ++t) {
      auto sA = __builtin_amdgcn_permlane32_swap(w[0][t], w[1][t], false, false);
      auto sB = __builtin_amdgcn_permlane16_swap(sA[0], sA[1], false, false);
      pa0[t] = sB[0]; pa0[t + 2] = sB[1];
      auto sC = __builtin_amdgcn_permlane32_swap(w[2][t], w[3][t], false, false);
      auto sD = __builtin_amdgcn_permlane16_swap(sC[0], sC[1], false, false);
      pa1[t] = sD[0]; pa1[t + 2] = sD[1];
    }
#else
    {
      const int basel = l15 + ((lq & 1) << 5);
#pragma unroll
      for (int t = 0; t < 2; ++t) {
        int sel0 = (lq & 2) ? (int)w[1][t] : (int)w[0][t];
        int sel1 = (lq & 2) ? (int)w[3][t] : (int)w[2][t];
        pa0[t]     = (unsigned)__shfl(sel0, basel);
        pa0[t + 2] = (unsigned)__shfl(sel0, basel + 16);
        pa1[t]     = (unsigned)__shfl(sel1, basel);
        pa1[t + 2] = (unsigned)__shfl(sel1, basel + 16);
      }
    }
#endif
    u32x4 ua = {pa0[0], pa0[1], pa0[2], pa0[3]};
    u32x4 ub = {pa1[0], pa1[1], pa1[2], pa1[3]};
    pA = __builtin_bit_cast(bf16x8, ua);
    pB = __builtin_bit_cast(bf16x8, ub);
  };

  // prologue
  stageKV(0, 0);
  __syncthreads();

  for (int jt = 0; jt < 32; ++jt) {
    const int buf = jt & 1;
    if (jt + 1 < 32) stageKV(buf ^ 1, jt + 1);

    // mask for THIS jt, grouped at top (consumed ~400cy later in smax)
    f32x4 mA[4], mB[4];
    const int jb = jt * 64;
#pragma unroll
    for (int nf = 0; nf < 4; ++nf) {
      mA[nf] = *(const f32x4*)(mptr0 + jb + nf * 16);
      mB[nf] = *(const f32x4*)(mptr1 + jb + nf * 16);
    }

    const unsigned bo4 = (unsigned)(buf << 14);
    const unsigned k0a = aks0 + bo4, k1a = aks1 + bo4;

    // --- K fragment batch: 8 asm ds_read_b128, one wait ---
    f32x4 t0, t1, t2, t3, t4, t5, t6, t7;
    DSR(t0, k0a, "0");    DSR(t1, k0a, "2048");
    DSR(t2, k0a, "4096"); DSR(t3, k0a, "6144");
    DSR(t4, k1a, "0");    DSR(t5, k1a, "2048");
    DSR(t6, k1a, "4096"); DSR(t7, k1a, "6144");
    asm volatile("s_waitcnt lgkmcnt(0)" ::: "memory");
    __builtin_amdgcn_sched_barrier(0);
    bf16x8 kf0[4] = { __builtin_bit_cast(bf16x8, t0), __builtin_bit_cast(bf16x8, t1),
                      __builtin_bit_cast(bf16x8, t2), __builtin_bit_cast(bf16x8, t3) };
    bf16x8 kf1[4] = { __builtin_bit_cast(bf16x8, t4), __builtin_bit_cast(bf16x8, t5),
                      __builtin_bit_cast(bf16x8, t6), __builtin_bit_cast(bf16x8, t7) };

    // QK^T swapped: s[mi][nf]: q=l15, n = nf*16 + lq*4 + r
    f32x4 s[2][4];
#pragma unroll
    for (int mi = 0; mi < 2; ++mi)
#pragma unroll
      for (int nf = 0; nf < 4; ++nf) {
        f32x4 z = {0.f, 0.f, 0.f, 0.f};
        s[mi][nf] = mfma16(kf0[nf], qf[mi][0], z);
      }
#pragma unroll
    for (int mi = 0; mi < 2; ++mi)
#pragma unroll
      for (int nf = 0; nf < 4; ++nf)
        s[mi][nf] = mfma16(kf1[nf], qf[mi][1], s[mi][nf]);

    // --- V fragment batch issued NOW: latency hides under softmax VALU ---
    f32x4 v0, v1, v2, v3, v4, v5, v6, v7;
    DSR(v0, k0a, "8192");  DSR(v1, k0a, "10240");
    DSR(v2, k0a, "12288"); DSR(v3, k0a, "14336");
    DSR(v4, k1a, "8192");  DSR(v5, k1a, "10240");
    DSR(v6, k1a, "12288"); DSR(v7, k1a, "14336");

    bf16x8 paA0, paB0, paA1, paB1;
    smax(mA, s[0], lsum0, paA0, paB0);
    smax(mB, s[1], lsum1, paA1, paB1);

    asm volatile("s_waitcnt lgkmcnt(0)" ::: "memory");
    __builtin_amdgcn_sched_barrier(0);
    bf16x8 vf0[4] = { __builtin_bit_cast(bf16x8, v0), __builtin_bit_cast(bf16x8, v1),
                      __builtin_bit_cast(bf16x8, v2), __builtin_bit_cast(bf16x8, v3) };
    bf16x8 vf1[4] = { __builtin_bit_cast(bf16x8, v4), __builtin_bit_cast(bf16x8, v5),
                      __builtin_bit_cast(bf16x8, v6), __builtin_bit_cast(bf16x8, v7) };

    // PV: shared V fragments feed both mi
#pragma unroll
    for (int nf = 0; nf < 4; ++nf) {
      o[0][nf] = mfma16(paA0, vf0[nf], o[0][nf]);
      o[1][nf] = mfma16(paA1, vf0[nf], o[1][nf]);
    }
#pragma unroll
    for (int nf = 0; nf < 4; ++nf) {
      o[0][nf] = mfma16(paB0, vf1[nf], o[0][nf]);
      o[1][nf] = mfma16(paB1, vf1[nf], o[1][nf]);
    }
    __syncthreads();
  }

  // normalize: lsum holds q=l15 partial over this lane's n-slice
  float va = lsum0, vb = lsum1;
  va += __shfl_xor(va, 16); va += __shfl_xor(va, 32);
  vb += __shfl_xor(vb, 16); vb += __shfl_xor(vb, 32);
  const float ri0 = 1.0f / va, ri1 = 1.0f / vb;
  float rv[2][4];
#pragma unroll
  for (int r = 0; r < 4; ++r) {
    rv[0][r] = __shfl(ri0, ((lane & 48) >> 2) + r);   // rinv of q = lq*4+r
    rv[1][r] = __shfl(ri1, ((lane & 48) >> 2) + r);
  }
#pragma unroll
  for (int mi = 0; mi < 2; ++mi)
#pragma unroll
    for (int nf = 0; nf < 4; ++nf)
#pragma unroll
      for (int r = 0; r < 4; ++r) {
        const long long rowg = (long long)b * 2048 + qrow0 + mi * 16 + lq * 4 + r;
        ao[rowg * 512 + h * 64 + nf * 16 + l15] = (bf16)(o[mi][nf][r] * rv[mi][r]);
      }
}

extern "C" void kernel_launch(void* const* d_in, const int* in_sizes, int n_in,
                              void* d_out, int out_size, void* d_ws, size_t ws_size,
                              hipStream_t stream) {
  const float* x    = (const float*)d_in[0];
  const float* mask = (const float*)d_in[1];
  const float* Wq   = (const float*)d_in[2];
  const float* Wk   = (const float*)d_in[3];
  const float* Wv   = (const float*)d_in[4];
  const float* Wo   = (const float*)d_in[5];
  const float* bo   = (const float*)d_in[6];
  float* out = (float*)d_out;
  char* ws = (char*)d_ws;

  const size_t SZ_XB = (size_t)16384 * 512 * 2;
  const size_t SZ_W3 = (size_t)1536 * 512 * 2;
  const size_t SZ_WO = (size_t)512 * 512 * 2;
  const size_t SZ_T  = (size_t)64 * 2048 * 64 * 2;

  bf16* xb    = (bf16*)ws;
  bf16* wqkvT = (bf16*)(ws + SZ_XB);
  bf16* woT   = (bf16*)(ws + SZ_XB + SZ_W3);
  bf16* qbuf  = (bf16*)(ws + SZ_XB + SZ_W3 + SZ_WO);
  bf16* kbuf  = (bf16*)((char*)qbuf + SZ_T);
  bf16* vtb   = (bf16*)((char*)kbuf + SZ_T);
  bf16* aob   = xb;  // x dead after QKV GEMM

  k_cvt_x<<<dim3(4096), dim3(256), 0, stream>>>(x, xb);
  k_wt<<<dim3(8, 8), dim3(256), 0, stream>>>(Wq, wqkvT);
  k_wt<<<dim3(8, 8), dim3(256), 0, stream>>>(Wk, wqkvT + 512 * 512);
  k_wt<<<dim3(8, 8), dim3(256), 0, stream>>>(Wv, wqkvT + 2 * 512 * 512);
  k_wt<<<dim3(8, 8), dim3(256), 0, stream>>>(Wo, woT);
  k_gemm<0><<<dim3(128, 12), dim3(256), 0, stream>>>(xb, wqkvT, qbuf, kbuf, vtb, nullptr, nullptr);
  k_attn<<<dim3(1024), dim3(256), 0, stream>>>(qbuf, kbuf, vtb, mask, aob);
  k_gemm<1><<<dim3(128, 4), dim3(256), 0, stream>>>(aob, woT, nullptr, nullptr, nullptr, out, bo);
}